// Round 1
// baseline (90.303 us; speedup 1.0000x reference)
//
#include <hip/hip_runtime.h>
#include <hip/hip_bf16.h>

typedef __bf16 bf16;
typedef __bf16 bf16x4 __attribute__((ext_vector_type(4)));
typedef __bf16 bf16x8 __attribute__((ext_vector_type(8)));
typedef float  f32x4  __attribute__((ext_vector_type(4)));

#define HID   128
#define BSZ   8
#define CDIM  512
#define QDIM  64
#define LDH   136   // padded LDS leading dim (bf16 elems), 272B rows: 16B aligned, breaks pow2 bank stride
#define CTILE 128

// One workgroup per (b,q). W_eff[k][d] = w_h[k][d] + u[d]*w_hu[k][d] folds
// h_proj+hu_proj into a single per-(b,q) GEMM: l1 = relu(h @ W_eff^T + bias),
// bias[k] = b1[k] + u.w_u[k]. Then out = relu(l1 @ w2 + b2), fused in-register.
__global__ __launch_bounds__(256, 2)
void sim_kernel(const float* __restrict__ hptr,
                const float* __restrict__ uptr,
                const float* __restrict__ w1,
                const float* __restrict__ b1,
                const float* __restrict__ w2,
                const float* __restrict__ b2,
                float* __restrict__ out)
{
    __shared__ bf16  weff[HID * LDH];    // [k_out][d]
    __shared__ bf16  hsh[CTILE * LDH];   // [c_local][d]
    __shared__ float ush[HID];
    __shared__ float bias_sh[HID];
    __shared__ float w2sh[HID];

    const int t  = threadIdx.x;
    const int bi = blockIdx.x >> 6;
    const int qi = blockIdx.x & 63;

    const float* uvec = uptr + (bi * QDIM + qi) * HID;

    if (t < HID) {
        ush[t]  = uvec[t];
        w2sh[t] = w2[t];
    }
    __syncthreads();

    // ---- build W_eff (bf16) : 2 threads per k-row, 64 d each ----
    {
        const int k     = t >> 1;
        const int dbase = (t & 1) * 64;
        const float* wrow = w1 + k * 384;
        #pragma unroll
        for (int j = 0; j < 16; ++j) {
            const int d = dbase + j * 4;
            float4 wh  = *(const float4*)(wrow + d);
            float4 whu = *(const float4*)(wrow + 256 + d);
            bf16x4 o;
            o[0] = (bf16)(wh.x + ush[d + 0] * whu.x);
            o[1] = (bf16)(wh.y + ush[d + 1] * whu.y);
            o[2] = (bf16)(wh.z + ush[d + 2] * whu.z);
            o[3] = (bf16)(wh.w + ush[d + 3] * whu.w);
            *(bf16x4*)&weff[k * LDH + d] = o;
        }
    }
    // ---- bias[k] = b1[k] + sum_d u[d]*w_u[k][d]  (fp32 exact) ----
    if (t < HID) {
        const float* wrow = w1 + t * 384 + 128;
        float acc = 0.f;
        #pragma unroll 8
        for (int d = 0; d < 128; d += 4) {
            float4 wu = *(const float4*)(wrow + d);
            acc += wu.x * ush[d] + wu.y * ush[d + 1] + wu.z * ush[d + 2] + wu.w * ush[d + 3];
        }
        bias_sh[t] = b1[t] + acc;
    }
    __syncthreads();

    const int lane = t & 63;
    const int wv   = t >> 6;      // wave 0..3 -> c rows [wv*32, wv*32+32)
    const int col  = lane & 15;   // MFMA n/m index
    const int quad = lane >> 4;   // MFMA k-group / row-group

    // ---- cache all B fragments (W_eff^T) in registers: 4 ksteps x 8 ntiles ----
    // B[kdim = quad*8+j][n = col] = W_eff[n][kdim]
    bf16x8 bfrag[4][8];
    #pragma unroll
    for (int ks = 0; ks < 4; ++ks)
        #pragma unroll
        for (int n = 0; n < 8; ++n)
            bfrag[ks][n] = *(const bf16x8*)&weff[(n * 16 + col) * LDH + ks * 32 + quad * 8];

    float bias_l[8], w2_l[8];
    #pragma unroll
    for (int n = 0; n < 8; ++n) {
        bias_l[n] = bias_sh[n * 16 + col];
        w2_l[n]   = w2sh[n * 16 + col];
    }
    const float b2v = b2[0];

    const float* hbase = hptr + bi * (CDIM * HID);
    float*       obase = out + (bi * CDIM) * QDIM + qi;

    for (int ct = 0; ct < CDIM / CTILE; ++ct) {
        __syncthreads();   // previous tile's LDS reads complete
        // ---- stage h tile (fp32 -> bf16), fully coalesced float4 loads ----
        {
            const int c0 = ct * CTILE;
            #pragma unroll
            for (int i = 0; i < 16; ++i) {
                const int flat4 = i * 256 + t;     // float4 index into 128x128 tile
                const int row   = flat4 >> 5;      // 32 float4 per row
                const int c4    = flat4 & 31;
                float4 v = *(const float4*)(hbase + (c0 + row) * HID + c4 * 4);
                bf16x4 o;
                o[0] = (bf16)v.x; o[1] = (bf16)v.y; o[2] = (bf16)v.z; o[3] = (bf16)v.w;
                *(bf16x4*)&hsh[row * LDH + c4 * 4] = o;
            }
        }
        __syncthreads();

        #pragma unroll
        for (int rt = 0; rt < 2; ++rt) {
            f32x4 acc[8];
            #pragma unroll
            for (int n = 0; n < 8; ++n) acc[n] = (f32x4){0.f, 0.f, 0.f, 0.f};

            #pragma unroll
            for (int ks = 0; ks < 4; ++ks) {
                // A[m = col][kdim = quad*8+j] from h tile rows [wv*32+rt*16, +16)
                bf16x8 a = *(const bf16x8*)&hsh[(wv * 32 + rt * 16 + col) * LDH + ks * 32 + quad * 8];
                #pragma unroll
                for (int n = 0; n < 8; ++n)
                    acc[n] = __builtin_amdgcn_mfma_f32_16x16x32_bf16(a, bfrag[ks][n], acc[n], 0, 0, 0);
            }

            // ---- fused epilogue: relu(l1)·w2, reduce over k, relu(+b2), store ----
            // D layout: row = quad*4 + reg, colk = n*16 + col
            float s0 = 0.f, s1 = 0.f, s2 = 0.f, s3 = 0.f;
            #pragma unroll
            for (int n = 0; n < 8; ++n) {
                const float bl = bias_l[n], wl = w2_l[n];
                s0 += fmaxf(acc[n][0] + bl, 0.f) * wl;
                s1 += fmaxf(acc[n][1] + bl, 0.f) * wl;
                s2 += fmaxf(acc[n][2] + bl, 0.f) * wl;
                s3 += fmaxf(acc[n][3] + bl, 0.f) * wl;
            }
            #pragma unroll
            for (int off = 1; off < 16; off <<= 1) {
                s0 += __shfl_xor(s0, off, 64);
                s1 += __shfl_xor(s1, off, 64);
                s2 += __shfl_xor(s2, off, 64);
                s3 += __shfl_xor(s3, off, 64);
            }
            if (col < 4) {
                const float sv = col == 0 ? s0 : col == 1 ? s1 : col == 2 ? s2 : s3;
                const int crow = ct * CTILE + wv * 32 + rt * 16 + quad * 4 + col;
                obase[crow * QDIM] = fmaxf(sv + b2v, 0.f);
            }
        }
    }
}

extern "C" void kernel_launch(void* const* d_in, const int* in_sizes, int n_in,
                              void* d_out, int out_size, void* d_ws, size_t ws_size,
                              hipStream_t stream) {
    const float* h  = (const float*)d_in[0];
    const float* u  = (const float*)d_in[1];
    const float* w1 = (const float*)d_in[2];
    const float* b1 = (const float*)d_in[3];
    const float* w2 = (const float*)d_in[4];
    const float* b2 = (const float*)d_in[5];
    float* out = (float*)d_out;

    sim_kernel<<<dim3(BSZ * QDIM), dim3(256), 0, stream>>>(h, u, w1, b1, w2, b2, out);
}